// Round 17
// baseline (220.702 us; speedup 1.0000x reference)
//
#include <hip/hip_runtime.h>
#include <hip/hip_bf16.h>
#include <math.h>

namespace {
constexpr int kNE   = 2048;
constexpr int kB    = 512;
constexpr int kDin  = 768;
constexpr int kD    = 512;
constexpr int kP    = 49;
constexpr int kNtot = kNE + kB;   // 2560
}

typedef __attribute__((ext_vector_type(8))) short bf16x8;
typedef __attribute__((ext_vector_type(4))) float f32x4;

__device__ inline ushort f2bf(float f) {  // RNE fp32 -> bf16 bits
  unsigned u = __float_as_uint(f);
  return (ushort)((u + 0x7fffu + ((u >> 16) & 1u)) >> 16);
}
// v = hi + lo (hi = truncate-to-bf16, exact; lo = rne(v - hi), ~2^-17 rel)
__device__ inline void split1(float v, ushort& h, ushort& l) {
  unsigned u = __float_as_uint(v);
  h = (ushort)(u >> 16);
  l = f2bf(v - __uint_as_float(u & 0xFFFF0000u));
}

// ---------------------------------------------------------------------------
// Job-batched compensated bf16x3 MFMA GEMM — 64x64 tile (R16-proven).
// 4 waves as 2x2, each 32x32 (acc 2x2). Reg-staged double-buffer,
// one barrier per K-tile. D = Ah*Bh + Al*Bh + Ah*Bl (fp32-grade).
// ---------------------------------------------------------------------------
struct GemmJob {
  const ushort *Ah, *Al;    // [M,K] bf16 hi/lo
  const ushort *Bh, *Bl;    // [N,K] bf16 hi/lo
  const float* bias;
  float* Cf;                // optional fp32 out
  ushort *Ch, *Cl;          // optional split out
  int M, N, K, relu;
};
struct GemmBatch { GemmJob j[6]; int prefix[7]; };

__global__ __launch_bounds__(256) void gemm_batch(GemmBatch batch) {
  int ji = 0;
  { const int bid = blockIdx.x;
    while (ji < 5 && bid >= batch.prefix[ji + 1]) ++ji; }
  const GemmJob jb = batch.j[ji];
  const int local = blockIdx.x - batch.prefix[ji];
  const int nbx = jb.N >> 6;
  const int by = local / nbx;
  const int bx = local - by * nbx;
  const int row0 = by * 64, col0 = bx * 64;
  const int K = jb.K;
  const int nt = K >> 5;

  __shared__ ushort Ahs[2][64][40], Als[2][64][40];   // +8 pad -> 80B stride
  __shared__ ushort Bhs[2][64][40], Bls[2][64][40];   // total 40 KB

  const int tid  = threadIdx.x;
  const int lane = tid & 63;
  const int w    = tid >> 6;
  const int wr   = (w >> 1) * 32;   // wave row offset
  const int wc   = (w & 1) * 32;    // wave col offset
  const int fr   = lane & 15;
  const int fk   = (lane >> 4) * 8;
  const int sr   = tid >> 2;        // staging row 0..63
  const int sk   = (tid & 3) * 8;   // staging k-chunk

  const ushort* pAh = jb.Ah + (size_t)(row0 + sr) * K + sk;
  const ushort* pAl = jb.Al + (size_t)(row0 + sr) * K + sk;
  const ushort* pBh = jb.Bh + (size_t)(col0 + sr) * K + sk;
  const ushort* pBl = jb.Bl + (size_t)(col0 + sr) * K + sk;

  bf16x8 rAh, rAl, rBh, rBl;        // in-flight tile (16 VGPR)
  auto LOAD = [&](int t) {
    const int o = t * 32;
    rAh = *(const bf16x8*)(pAh + o); rAl = *(const bf16x8*)(pAl + o);
    rBh = *(const bf16x8*)(pBh + o); rBl = *(const bf16x8*)(pBl + o);
  };
  auto STORE = [&](int b) {
    *(bf16x8*)&Ahs[b][sr][sk] = rAh; *(bf16x8*)&Als[b][sr][sk] = rAl;
    *(bf16x8*)&Bhs[b][sr][sk] = rBh; *(bf16x8*)&Bls[b][sr][sk] = rBl;
  };

  f32x4 acc[2][2] = {};

  LOAD(0); STORE(0);
  if (nt > 1) LOAD(1);
  __syncthreads();

  for (int t = 0; t < nt; ++t) {
    const int cur = t & 1;
    bf16x8 bh[2], bl[2], ah[2], al[2];
#pragma unroll
    for (int n = 0; n < 2; ++n) {
      bh[n] = *(const bf16x8*)&Bhs[cur][wc + n * 16 + fr][fk];
      bl[n] = *(const bf16x8*)&Bls[cur][wc + n * 16 + fr][fk];
    }
#pragma unroll
    for (int m = 0; m < 2; ++m) {
      ah[m] = *(const bf16x8*)&Ahs[cur][wr + m * 16 + fr][fk];
      al[m] = *(const bf16x8*)&Als[cur][wr + m * 16 + fr][fk];
    }
#pragma unroll
    for (int m = 0; m < 2; ++m)
#pragma unroll
      for (int n = 0; n < 2; ++n) {
        acc[m][n] = __builtin_amdgcn_mfma_f32_16x16x32_bf16(ah[m], bh[n], acc[m][n], 0, 0, 0);
        acc[m][n] = __builtin_amdgcn_mfma_f32_16x16x32_bf16(al[m], bh[n], acc[m][n], 0, 0, 0);
        acc[m][n] = __builtin_amdgcn_mfma_f32_16x16x32_bf16(ah[m], bl[n], acc[m][n], 0, 0, 0);
      }
    if (t + 1 < nt) {
      STORE(cur ^ 1);                // tile t+1 regs -> other buffer
      if (t + 2 < nt) LOAD(t + 2);   // prefetch tile t+2
    }
    __syncthreads();                 // single barrier per K-tile
  }

  // epilogue: C/D layout col = lane&15, row = (lane>>4)*4 + j  [m89-verified]
  const int fq = lane >> 4;
#pragma unroll
  for (int n = 0; n < 2; ++n) {
    const int col = col0 + wc + n * 16 + fr;
    const float bv = jb.bias ? jb.bias[col] : 0.f;
#pragma unroll
    for (int m = 0; m < 2; ++m) {
      const int rbase = row0 + wr + m * 16 + fq * 4;
#pragma unroll
      for (int jj = 0; jj < 4; ++jj) {
        float v = acc[m][n][jj] + bv;
        if (jb.relu) v = fmaxf(v, 0.f);
        const size_t idx = (size_t)(rbase + jj) * jb.N + col;
        if (jb.Cf) jb.Cf[idx] = v;
        if (jb.Ch) { ushort h, l; split1(v, h, l); jb.Ch[idx] = h; jb.Cl[idx] = l; }
      }
    }
  }
}

// ---------------------------------------------------------------------------
// ONE prep dispatch: 5 plain splits + 7 transpose+splits + 2 PARALLEL gemvs.
// ---------------------------------------------------------------------------
struct SplitJob { const float* src; ushort* hi; ushort* lo; int n4; };
struct TSJob { const float* src; ushort* hi; ushort* lo; int R, C; };
struct PrepArgs {
  SplitJob s[5];
  TSJob t[7];
  const float *img_b, *match_w, *match_b, *mh_wv, *mh_bv;
  float *bcomb;
  ushort *bt1pad_h, *bt1pad_l;      // [64,512], row 0 = split(bt1)
  int prefix[15];
};

__global__ __launch_bounds__(256) void prep_all(PrepArgs a) {
  int ji = 0;
  { const int bid = blockIdx.x;
    while (ji < 13 && bid >= a.prefix[ji + 1]) ++ji; }
  const int local = blockIdx.x - a.prefix[ji];
  const int t = threadIdx.x;
  __shared__ float tl[32][33];
  __shared__ float rr[4];

  if (ji < 5) {                       // plain split
    const SplitJob jb = a.s[ji];
    const int i = local * 256 + t;
    if (i < jb.n4) {
      float4 v = *(const float4*)&jb.src[(size_t)i * 4];
      ushort4 h, l;
      split1(v.x, h.x, l.x); split1(v.y, h.y, l.y);
      split1(v.z, h.z, l.z); split1(v.w, h.w, l.w);
      *(ushort4*)&jb.hi[(size_t)i * 4] = h;
      *(ushort4*)&jb.lo[(size_t)i * 4] = l;
    }
  } else if (ji < 12) {               // transpose + split
    const TSJob jb = a.t[ji - 5];
    const int ntx = jb.C / 32;
    const int r0 = (local / ntx) * 32, c0 = (local % ntx) * 32;
    const int tx = t & 31, ty = t >> 5;  // 32x8
#pragma unroll
    for (int i = 0; i < 32; i += 8)
      tl[ty + i][tx] = jb.src[(size_t)(r0 + ty + i) * jb.C + c0 + tx];
    __syncthreads();
#pragma unroll
    for (int i = 0; i < 32; i += 8) {
      ushort h, l; split1(tl[tx][ty + i], h, l);
      const size_t idx = (size_t)(c0 + ty + i) * jb.R + r0 + tx;
      jb.hi[idx] = h; jb.lo[idx] = l;
    }
  } else {                            // parallel gemv, 1 block per column
    const int j = local;              // 0..511
    const float* vec  = (ji == 12) ? a.img_b : a.match_b;
    const float* W    = (ji == 12) ? a.match_w : a.mh_wv;
    const float* badd = (ji == 12) ? a.match_b : a.mh_bv;
    float acc = 0.f;
    for (int k = t; k < kD; k += 256) acc = fmaf(vec[k], W[(size_t)k * kD + j], acc);
    for (int o = 32; o; o >>= 1) acc += __shfl_xor(acc, o);
    if ((t & 63) == 0) rr[t >> 6] = acc;
    __syncthreads();
    if (t == 0) {
      const float v = rr[0] + rr[1] + rr[2] + rr[3] + badd[j];
      if (ji == 12) a.bcomb[j] = v;
      else { ushort h, l; split1(v, h, l); a.bt1pad_h[j] = h; a.bt1pad_l[j] = l; }
    }
  }
}

// ---------------------------------------------------------------------------
// HETEROGENEOUS: blocks [0,320) = img GEMM (single-buffer 64x64, 20.5KB
// LDS union) ; rest = wave-local float4 pool. R17: shrinking the union
// 30.7KB -> 20.5KB raises pool occupancy 5 -> 7 blocks/CU (20 -> 28 waves)
// for the 385MB HBM stream.
// ---------------------------------------------------------------------------
struct PoolImgArgs {
  GemmJob g; int gemmBlocks;
  const float *ent_toks, *men_toks, *u;
  ushort *wh, *wl;
};

__global__ __launch_bounds__(256) void pool_img(PoolImgArgs a) {
  __shared__ ushort smem[10240];     // 20480 B union
  __shared__ float sm[4], sl[4];
  const int t = threadIdx.x;
  const int lane = t & 63, wave = t >> 6;

  if ((int)blockIdx.x < a.gemmBlocks) {
    ushort (*Ahs)[40] = (ushort(*)[40])&smem[0];
    ushort (*Als)[40] = (ushort(*)[40])&smem[2560];
    ushort (*Bhs)[40] = (ushort(*)[40])&smem[5120];
    ushort (*Bls)[40] = (ushort(*)[40])&smem[7680];
    const GemmJob jb = a.g;
    const int local = blockIdx.x;
    const int nbx = jb.N >> 6;
    const int by = local / nbx, bx = local - by * nbx;
    const int row0 = by * 64, col0 = bx * 64;
    const int K = jb.K;
    const int wr = (wave >> 1) * 32, wc = (wave & 1) * 32;
    const int fr = lane & 15, fk = (lane >> 4) * 8;
    const int sr = t >> 2, sk = (t & 3) * 8;
    f32x4 acc[2][2] = {};
    for (int k0 = 0; k0 < K; k0 += 32) {
      *(bf16x8*)&Ahs[sr][sk] = *(const bf16x8*)&jb.Ah[(size_t)(row0 + sr) * K + k0 + sk];
      *(bf16x8*)&Als[sr][sk] = *(const bf16x8*)&jb.Al[(size_t)(row0 + sr) * K + k0 + sk];
      *(bf16x8*)&Bhs[sr][sk] = *(const bf16x8*)&jb.Bh[(size_t)(col0 + sr) * K + k0 + sk];
      *(bf16x8*)&Bls[sr][sk] = *(const bf16x8*)&jb.Bl[(size_t)(col0 + sr) * K + k0 + sk];
      __syncthreads();
      bf16x8 bh[2], bl[2], ah[2], al[2];
#pragma unroll
      for (int n = 0; n < 2; ++n) {
        bh[n] = *(const bf16x8*)&Bhs[wc + n * 16 + fr][fk];
        bl[n] = *(const bf16x8*)&Bls[wc + n * 16 + fr][fk];
      }
#pragma unroll
      for (int m = 0; m < 2; ++m) {
        ah[m] = *(const bf16x8*)&Ahs[wr + m * 16 + fr][fk];
        al[m] = *(const bf16x8*)&Als[wr + m * 16 + fr][fk];
      }
#pragma unroll
      for (int m = 0; m < 2; ++m)
#pragma unroll
        for (int n = 0; n < 2; ++n) {
          acc[m][n] = __builtin_amdgcn_mfma_f32_16x16x32_bf16(ah[m], bh[n], acc[m][n], 0, 0, 0);
          acc[m][n] = __builtin_amdgcn_mfma_f32_16x16x32_bf16(al[m], bh[n], acc[m][n], 0, 0, 0);
          acc[m][n] = __builtin_amdgcn_mfma_f32_16x16x32_bf16(ah[m], bl[n], acc[m][n], 0, 0, 0);
        }
      __syncthreads();
    }
    const int fq = lane >> 4;
#pragma unroll
    for (int n = 0; n < 2; ++n) {
      const int col = col0 + wc + n * 16 + fr;
      const float bv = jb.bias ? jb.bias[col] : 0.f;
#pragma unroll
      for (int m = 0; m < 2; ++m) {
        const int rbase = row0 + wr + m * 16 + fq * 4;
#pragma unroll
        for (int jj = 0; jj < 4; ++jj) {
          float v = acc[m][n][jj] + bv;
          if (jb.relu) v = fmaxf(v, 0.f);
          const size_t idx = (size_t)(rbase + jj) * jb.N + col;
          if (jb.Cf) jb.Cf[idx] = v;
          if (jb.Ch) { ushort h, l; split1(v, h, l); jb.Ch[idx] = h; jb.Cl[idx] = l; }
        }
      }
    }
    return;
  }

  // -------- pool path (float4 loads; lane owns dims 4*lane + 256*r) --------
  float* sacc = (float*)smem;        // [4][768] f32 = 12288 B < 20480
  const int n = blockIdx.x - a.gemmBlocks;
  const float* toks = (n < kNE) ? a.ent_toks + (size_t)n * kP * kDin
                                : a.men_toks + (size_t)(n - kNE) * kP * kDin;
  const float* un = a.u + (size_t)n * kDin;
  const float scale = 0.044194173824159216f;  // 512^-0.5

  f32x4 ureg[3];
#pragma unroll
  for (int r = 0; r < 3; ++r) ureg[r] = *(const f32x4*)&un[4 * lane + 256 * r];

  float m = -INFINITY, l = 0.f;
  f32x4 acc[3] = {};

  for (int p = wave; p < kP; p += 4) {
    const float* tp = toks + (size_t)p * kDin;
    f32x4 tv[3];
#pragma unroll
    for (int r = 0; r < 3; ++r) tv[r] = *(const f32x4*)&tp[4 * lane + 256 * r];
    float d = 0.f;
#pragma unroll
    for (int r = 0; r < 3; ++r)
#pragma unroll
      for (int i = 0; i < 4; ++i) d = fmaf(tv[r][i], ureg[r][i], d);
    for (int o = 32; o; o >>= 1) d += __shfl_xor(d, o);   // wave-local reduce
    const float s = d * scale;
    const float mn = fmaxf(m, s);
    const float c = __expf(m - mn);   // 0 on first iter (m=-inf)
    const float e = __expf(s - mn);
    l = l * c + e;
#pragma unroll
    for (int r = 0; r < 3; ++r) acc[r] = acc[r] * c + tv[r] * e;
    m = mn;
  }

  // combine 4 wave-partials (one barrier)
#pragma unroll
  for (int r = 0; r < 3; ++r)
    *(f32x4*)&sacc[wave * kDin + 4 * lane + 256 * r] = acc[r];
  if (lane == 0) { sm[wave] = m; sl[wave] = l; }
  __syncthreads();

  const float M = fmaxf(fmaxf(sm[0], sm[1]), fmaxf(sm[2], sm[3]));
  const float c0 = __expf(sm[0] - M), c1 = __expf(sm[1] - M);
  const float c2 = __expf(sm[2] - M), c3 = __expf(sm[3] - M);
  const float inv = 1.f / (sl[0] * c0 + sl[1] * c1 + sl[2] * c2 + sl[3] * c3);

  const size_t base = (size_t)n * kDin;
#pragma unroll
  for (int r = 0; r < 3; ++r) {
    const int dd = t + r * 256;
    const float v = (sacc[0 * kDin + dd] * c0 + sacc[1 * kDin + dd] * c1 +
                     sacc[2 * kDin + dd] * c2 + sacc[3 * kDin + dd] * c3) * inv;
    ushort h, lo; split1(v, h, lo);
    a.wh[base + dd] = h; a.wl[base + dd] = lo;
  }
}

// ---------------------------------------------------------------------------
// Finalize with fused MoE gate (unchanged, R13-proven).
// ---------------------------------------------------------------------------
__global__ __launch_bounds__(256) void finalize_ln(
    const float* __restrict__ cls_p, const float* __restrict__ et,
    const float* __restrict__ ei, const float* __restrict__ txt,
    const float* __restrict__ img,
    const float* __restrict__ gw, const float* __restrict__ gb,
    const float* __restrict__ gfw, const float* __restrict__ gfb,
    const float* __restrict__ lng, const float* __restrict__ lnb,
    ushort* __restrict__ ch, ushort* __restrict__ cl) {
  const int n = blockIdx.x;
  const int t = threadIdx.x;
  const int lane = t & 63, wave = t >> 6;
  const size_t base = (size_t)n * kD;
  const float c0 = cls_p[base + t], c1 = cls_p[base + 256 + t];

  const float t0 = txt[base + t], t1 = txt[base + 256 + t];
  const float i0 = img[base + t], i1 = img[base + 256 + t];
  float d  = fmaf(c0, gfw[t], c1 * gfw[t + 256]);
  float p0 = fmaf(t0, gw[t * 2 + 0], fmaf(t1, gw[(t + 256) * 2 + 0],
             fmaf(i0, gw[(512 + t) * 2 + 0], i1 * gw[(768 + t) * 2 + 0])));
  float p1 = fmaf(t0, gw[t * 2 + 1], fmaf(t1, gw[(t + 256) * 2 + 1],
             fmaf(i0, gw[(512 + t) * 2 + 1], i1 * gw[(768 + t) * 2 + 1])));
  for (int o = 32; o; o >>= 1) {
    d += __shfl_xor(d, o); p0 += __shfl_xor(p0, o); p1 += __shfl_xor(p1, o);
  }
  __shared__ float rd[4], r0[4], r1[4];
  __shared__ float gtb, g0b, g1b;
  if (lane == 0) { rd[wave] = d; r0[wave] = p0; r1[wave] = p1; }
  __syncthreads();
  if (t == 0) {
    gtb = tanhf(rd[0] + rd[1] + rd[2] + rd[3] + gfb[0]);
    const float l0 = r0[0] + r0[1] + r0[2] + r0[3] + gb[0];
    const float l1 = r1[0] + r1[1] + r1[2] + r1[3] + gb[1];
    const float mm = fmaxf(l0, l1);
    const float e0 = __expf(l0 - mm), e1 = __expf(l1 - mm);
    const float inv = 1.f / (e0 + e1);
    g0b = e0 * inv; g1b = e1 * inv;
  }
  __syncthreads();
  const float gt = gtb, g0 = g0b, g1 = g1b;

  const float y0 = c0 * gt + g0 * et[base + t]       + g1 * ei[base + t];
  const float y1 = c1 * gt + g0 * et[base + 256 + t] + g1 * ei[base + 256 + t];

  float s = y0 + y1, ss = fmaf(y0, y0, y1 * y1);
  for (int o = 32; o; o >>= 1) { s += __shfl_xor(s, o); ss += __shfl_xor(ss, o); }
  __shared__ float rsum[4], rssq[4];
  __shared__ float mb, ivb;
  if (lane == 0) { rsum[wave] = s; rssq[wave] = ss; }
  __syncthreads();
  if (t == 0) {
    const float S  = rsum[0] + rsum[1] + rsum[2] + rsum[3];
    const float SS = rssq[0] + rssq[1] + rssq[2] + rssq[3];
    const float mm = S / (float)kD;
    const float v  = SS / (float)kD - mm * mm;
    mb = mm; ivb = rsqrtf(v + 1e-5f);
  }
  __syncthreads();
  const float mm = mb, iv = ivb;
  ushort h, l;
  split1((y0 - mm) * iv * lng[t] + lnb[t], h, l);
  ch[base + t] = h; cl[base + t] = l;
  split1((y1 - mm) * iv * lng[t + 256] + lnb[t + 256], h, l);
  ch[base + 256 + t] = h; cl[base + 256 + t] = l;
}

// ---------------------------------------------------------------------------
extern "C" void kernel_launch(void* const* d_in, const int* in_sizes, int n_in,
                              void* d_out, int out_size, void* d_ws, size_t ws_size,
                              hipStream_t stream) {
  const float* ent_cls  = (const float*)d_in[0];
  const float* ent_tok  = (const float*)d_in[1];
  const float* men_cls  = (const float*)d_in[2];
  const float* men_tok  = (const float*)d_in[3];
  const float* text_w   = (const float*)d_in[4];
  const float* text_b   = (const float*)d_in[5];
  const float* img_w    = (const float*)d_in[6];
  const float* img_b    = (const float*)d_in[7];
  const float* gate_w   = (const float*)d_in[8];
  const float* gate_b   = (const float*)d_in[9];
  const float* ln_g     = (const float*)d_in[10];
  const float* ln_b     = (const float*)d_in[11];
  const float* match_w  = (const float*)d_in[12];
  const float* match_b  = (const float*)d_in[13];
  // d_in[14..18] (mh_query, mh_wq, mh_bq, mh_wk, mh_bk) provably unused
  const float* mh_wv    = (const float*)d_in[19];
  const float* mh_bv    = (const float*)d_in[20];
  const float* mh_wo    = (const float*)d_in[21];
  const float* mh_bo    = (const float*)d_in[22];
  const float* moe_gw   = (const float*)d_in[23];
  const float* moe_gb   = (const float*)d_in[24];
  const float* moe_tw1  = (const float*)d_in[25];
  const float* moe_tb1  = (const float*)d_in[26];
  const float* moe_tw2  = (const float*)d_in[27];
  const float* moe_tb2  = (const float*)d_in[28];
  const float* moe_iw1  = (const float*)d_in[29];
  const float* moe_ib1  = (const float*)d_in[30];
  const float* moe_iw2  = (const float*)d_in[31];
  const float* moe_ib2  = (const float*)d_in[32];
  (void)ws_size; (void)n_in; (void)in_sizes; (void)out_size;

  char* base = (char*)d_ws;
  size_t off = 0;
  auto allocB = [&](size_t bytes) -> char* {
    char* p = base + off; off = (off + bytes + 255) & ~(size_t)255; return p;
  };
  auto allocF = [&](size_t n) { return (float*)allocB(n * 4); };
  auto allocU = [&](size_t n) { return (ushort*)allocB(n * 2); };

  // fp32 intermediates
  float* clsp_f = allocF((size_t)kNtot * kD);
  float* u_f    = allocF((size_t)kNtot * kDin);
  float* txt_f  = allocF((size_t)kNtot * kD);
  float* img_f  = allocF((size_t)kNtot * kD);
  float* et_f   = allocF((size_t)kNtot * kD);
  float* ei_f   = allocF((size_t)kNtot * kD);
  float* bcomb  = allocF(kD);
  float* bimg_pad = allocF((size_t)64 * kD);     // row 0 = bimg
  // split pairs
  auto pair = [&](size_t n, ushort*& h, ushort*& l) { h = allocU(n); l = allocU(n); };
  ushort *ent_h,*ent_l,*men_h,*men_l,*imgw_h,*imgw_l,*matw_h,*matw_l,*mhwv_h,*mhwv_l;
  pair((size_t)kNE * kDin, ent_h, ent_l);
  pair((size_t)kB * kDin, men_h, men_l);
  pair((size_t)kDin * kD, imgw_h, imgw_l);
  pair((size_t)kD * kD, matw_h, matw_l);
  pair((size_t)kD * kD, mhwv_h, mhwv_l);
  ushort *textWT_h,*textWT_l,*matchWT_h,*matchWT_l,*mhWoT_h,*mhWoT_l;
  ushort *tw1T_h,*tw1T_l,*tw2T_h,*tw2T_l,*iw1T_h,*iw1T_l,*iw2T_h,*iw2T_l;
  pair((size_t)kD * kDin, textWT_h, textWT_l);
  pair((size_t)kD * kD, matchWT_h, matchWT_l);
  pair((size_t)kD * kD, mhWoT_h, mhWoT_l);
  pair((size_t)kD * kD, tw1T_h, tw1T_l);
  pair((size_t)kD * kD, tw2T_h, tw2T_l);
  pair((size_t)kD * kD, iw1T_h, iw1T_l);
  pair((size_t)kD * kD, iw2T_h, iw2T_l);
  ushort *clsp_h,*clsp_l,*U_h,*U_l,*WcombT_h,*WcombT_l,*WimgT_h,*WimgT_l;
  ushort *bt1pad_h,*bt1pad_l;
  pair((size_t)kNtot * kD, clsp_h, clsp_l);
  pair((size_t)kD * kD, U_h, U_l);
  pair((size_t)kD * kDin, WcombT_h, WcombT_l);
  pair((size_t)kD * kD, WimgT_h, WimgT_l);
  pair((size_t)64 * kD, bt1pad_h, bt1pad_l);     // rows 1-63 unused
  ushort *ws_h,*ws_l,*txt_h,*txt_l,*img_h,*img_l,*ht_h,*ht_l,*hi_h,*hi_l,*ctx_h,*ctx_l;
  pair((size_t)kNtot * kDin, ws_h, ws_l);
  pair((size_t)kNtot * kD, txt_h, txt_l);
  pair((size_t)kNtot * kD, img_h, img_l);
  pair((size_t)kNtot * kD, ht_h, ht_l);
  pair((size_t)kNtot * kD, hi_h, hi_l);
  pair((size_t)kNtot * kD, ctx_h, ctx_l);

  auto nblk = [](const GemmJob& j) { return (j.M / 64) * (j.N / 64); };
  auto launch_batch = [&](int njobs, GemmJob j0, GemmJob j1 = {}, GemmJob j2 = {},
                          GemmJob j3 = {}, GemmJob j4 = {}, GemmJob j5 = {}) {
    GemmBatch b{};
    b.j[0] = j0; b.j[1] = j1; b.j[2] = j2; b.j[3] = j3; b.j[4] = j4; b.j[5] = j5;
    b.prefix[0] = 0;
    for (int i = 0; i < 6; ++i)
      b.prefix[i + 1] = b.prefix[i] + (i < njobs ? nblk(b.j[i]) : 0);
    hipLaunchKernelGGL(gemm_batch, dim3(b.prefix[njobs]), 256, 0, stream, b);
  };

  // P0: ONE prep dispatch (5 splits + 7 trans-splits + 2 parallel gemvs)
  PrepArgs pa{};
  pa.s[0] = { ent_cls, ent_h, ent_l, kNE * kDin / 4 };
  pa.s[1] = { men_cls, men_h, men_l, kB * kDin / 4 };
  pa.s[2] = { img_w,   imgw_h, imgw_l, kDin * kD / 4 };
  pa.s[3] = { match_w, matw_h, matw_l, kD * kD / 4 };
  pa.s[4] = { mh_wv,   mhwv_h, mhwv_l, kD * kD / 4 };
  pa.t[0] = { text_w,  textWT_h,  textWT_l,  kDin, kD };
  pa.t[1] = { match_w, matchWT_h, matchWT_l, kD,   kD };
  pa.t[2] = { mh_wo,   mhWoT_h,   mhWoT_l,   kD,   kD };
  pa.t[3] = { moe_tw1, tw1T_h,    tw1T_l,    kD,   kD };
  pa.t[4] = { moe_tw2, tw2T_h,    tw2T_l,    kD,   kD };
  pa.t[5] = { moe_iw1, iw1T_h,    iw1T_l,    kD,   kD };
  pa.t[6] = { moe_iw2, iw2T_h,    iw2T_l,    kD,   kD };
  pa.img_b = img_b; pa.match_w = match_w; pa.match_b = match_b;
  pa.mh_wv = mh_wv; pa.mh_bv = mh_bv;
  pa.bcomb = bcomb; pa.bt1pad_h = bt1pad_h; pa.bt1pad_l = bt1pad_l;
  {
    int pfx = 0; int c = 0;
    pa.prefix[c++] = 0;
    for (int i = 0; i < 5; ++i) { pfx += (pa.s[i].n4 + 255) / 256; pa.prefix[c++] = pfx; }
    for (int i = 0; i < 7; ++i) { pfx += (pa.t[i].R / 32) * (pa.t[i].C / 32); pa.prefix[c++] = pfx; }
    for (int i = 0; i < 2; ++i) { pfx += kD; pa.prefix[c++] = pfx; }
    hipLaunchKernelGGL(prep_all, dim3(pfx), 256, 0, stream, pa);
  }

  // G1: clsp(ent), clsp(men), WcombT, U, bimg_pad = bt1pad@mhWoT^T + mh_bo
  launch_batch(5,
    GemmJob{ ent_h, ent_l, textWT_h, textWT_l, text_b,
             clsp_f, clsp_h, clsp_l, kNE, kD, kDin, 0 },
    GemmJob{ men_h, men_l, textWT_h, textWT_l, text_b,
             clsp_f + (size_t)kNE * kD, clsp_h + (size_t)kNE * kD,
             clsp_l + (size_t)kNE * kD, kB, kD, kDin, 0 },
    GemmJob{ matchWT_h, matchWT_l, imgw_h, imgw_l, nullptr,
             nullptr, WcombT_h, WcombT_l, kD, kDin, kD, 0 },
    GemmJob{ mhWoT_h, mhWoT_l, mhwv_h, mhwv_l, nullptr,
             nullptr, U_h, U_l, kD, kD, kD, 0 },
    GemmJob{ bt1pad_h, bt1pad_l, mhWoT_h, mhWoT_l, mh_bo,
             bimg_pad, nullptr, nullptr, 64, kD, kD, 0 });

  // G2: u = cls_p@img_w^T (fp32 only, K=512), WimgT = U@match_w^T
  launch_batch(2,
    GemmJob{ clsp_h, clsp_l, imgw_h, imgw_l, nullptr,
             u_f, nullptr, nullptr, kNtot, kDin, kD, 0 },
    GemmJob{ U_h, U_l, matw_h, matw_l, nullptr,
             nullptr, WimgT_h, WimgT_l, kD, kD, kD, 0 });

  // M1: img GEMM (320 blocks, 64x64, pool-independent) + float4 pool (2560)
  {
    PoolImgArgs pia{};
    pia.g = GemmJob{ clsp_h, clsp_l, WimgT_h, WimgT_l, bimg_pad,
                     img_f, img_h, img_l, kNtot, kD, kD, 0 };
    pia.gemmBlocks = (kNtot / 64) * (kD / 64);   // 320
    pia.ent_toks = ent_tok; pia.men_toks = men_tok; pia.u = u_f;
    pia.wh = ws_h; pia.wl = ws_l;
    hipLaunchKernelGGL(pool_img, dim3(pia.gemmBlocks + kNtot), 256, 0, stream, pia);
  }

  // G3: txt = ws@Wcomb + bcomb ; hi = relu(img@iw1T)   [640 blocks]
  launch_batch(2,
    GemmJob{ ws_h, ws_l, WcombT_h, WcombT_l, bcomb,
             txt_f, txt_h, txt_l, kNtot, kD, kDin, 0 },
    GemmJob{ img_h, img_l, iw1T_h, iw1T_l, moe_ib1,
             nullptr, hi_h, hi_l, kNtot, kD, kD, 1 });

  // G4: ht = relu(txt@tw1T) ; ei = hi@iw2T   [640 blocks]
  launch_batch(2,
    GemmJob{ txt_h, txt_l, tw1T_h, tw1T_l, moe_tb1,
             nullptr, ht_h, ht_l, kNtot, kD, kD, 1 },
    GemmJob{ hi_h, hi_l, iw2T_h, iw2T_l, moe_ib2,
             ei_f, nullptr, nullptr, kNtot, kD, kD, 0 });

  // G5: et = ht@tw2T   [320 blocks]
  launch_batch(1,
    GemmJob{ ht_h, ht_l, tw2T_h, tw2T_l, moe_tb2,
             et_f, nullptr, nullptr, kNtot, kD, kD, 0 });

  // P2: finalize (fused moe-gate + tanh-gate + combine + LN) -> ctx (split)
  hipLaunchKernelGGL(finalize_ln, dim3(kNtot), 256, 0, stream,
                     clsp_f, et_f, ei_f, txt_f, img_f,
                     moe_gw, moe_gb, gate_w, gate_b, ln_g, ln_b, ctx_h, ctx_l);

  // G6: out = m_ctx @ e_ctx^T
  launch_batch(1,
    GemmJob{ ctx_h + (size_t)kNE * kD, ctx_l + (size_t)kNE * kD,
             ctx_h, ctx_l, nullptr,
             (float*)d_out, nullptr, nullptr, kB, kNE, kD, 0 });
}

// Round 19
// 219.114 us; speedup vs baseline: 1.0072x; 1.0072x over previous
//
#include <hip/hip_runtime.h>
#include <hip/hip_bf16.h>
#include <math.h>

namespace {
constexpr int kNE   = 2048;
constexpr int kB    = 512;
constexpr int kDin  = 768;
constexpr int kD    = 512;
constexpr int kP    = 49;
constexpr int kNtot = kNE + kB;   // 2560
}

typedef __attribute__((ext_vector_type(8))) short bf16x8;
typedef __attribute__((ext_vector_type(4))) float f32x4;

__device__ inline ushort f2bf(float f) {  // RNE fp32 -> bf16 bits
  unsigned u = __float_as_uint(f);
  return (ushort)((u + 0x7fffu + ((u >> 16) & 1u)) >> 16);
}
// v = hi + lo (hi = truncate-to-bf16, exact; lo = rne(v - hi), ~2^-17 rel)
__device__ inline void split1(float v, ushort& h, ushort& l) {
  unsigned u = __float_as_uint(v);
  h = (ushort)(u >> 16);
  l = f2bf(v - __uint_as_float(u & 0xFFFF0000u));
}

// ---------------------------------------------------------------------------
// Job-batched compensated bf16x3 MFMA GEMM — 64x64 TILE (R16-proven best).
// 4 waves as 2x2, each 32x32 (acc 2x2). Reg-staged double-buffer,
// one barrier per K-tile. D = Ah*Bh + Al*Bh + Ah*Bl (fp32-grade).
// ---------------------------------------------------------------------------
struct GemmJob {
  const ushort *Ah, *Al;    // [M,K] bf16 hi/lo
  const ushort *Bh, *Bl;    // [N,K] bf16 hi/lo
  const float* bias;
  float* Cf;                // optional fp32 out
  ushort *Ch, *Cl;          // optional split out
  int M, N, K, relu;
};
struct GemmBatch { GemmJob j[6]; int prefix[7]; };

__global__ __launch_bounds__(256) void gemm_batch(GemmBatch batch) {
  int ji = 0;
  { const int bid = blockIdx.x;
    while (ji < 5 && bid >= batch.prefix[ji + 1]) ++ji; }
  const GemmJob jb = batch.j[ji];
  const int local = blockIdx.x - batch.prefix[ji];
  const int nbx = jb.N >> 6;
  const int by = local / nbx;
  const int bx = local - by * nbx;
  const int row0 = by * 64, col0 = bx * 64;
  const int K = jb.K;
  const int nt = K >> 5;

  __shared__ ushort Ahs[2][64][40], Als[2][64][40];   // +8 pad -> 80B stride
  __shared__ ushort Bhs[2][64][40], Bls[2][64][40];   // total 40 KB

  const int tid  = threadIdx.x;
  const int lane = tid & 63;
  const int w    = tid >> 6;
  const int wr   = (w >> 1) * 32;   // wave row offset
  const int wc   = (w & 1) * 32;    // wave col offset
  const int fr   = lane & 15;
  const int fk   = (lane >> 4) * 8;
  const int sr   = tid >> 2;        // staging row 0..63
  const int sk   = (tid & 3) * 8;   // staging k-chunk

  const ushort* pAh = jb.Ah + (size_t)(row0 + sr) * K + sk;
  const ushort* pAl = jb.Al + (size_t)(row0 + sr) * K + sk;
  const ushort* pBh = jb.Bh + (size_t)(col0 + sr) * K + sk;
  const ushort* pBl = jb.Bl + (size_t)(col0 + sr) * K + sk;

  bf16x8 rAh, rAl, rBh, rBl;        // in-flight tile (16 VGPR)
  auto LOAD = [&](int t) {
    const int o = t * 32;
    rAh = *(const bf16x8*)(pAh + o); rAl = *(const bf16x8*)(pAl + o);
    rBh = *(const bf16x8*)(pBh + o); rBl = *(const bf16x8*)(pBl + o);
  };
  auto STORE = [&](int b) {
    *(bf16x8*)&Ahs[b][sr][sk] = rAh; *(bf16x8*)&Als[b][sr][sk] = rAl;
    *(bf16x8*)&Bhs[b][sr][sk] = rBh; *(bf16x8*)&Bls[b][sr][sk] = rBl;
  };

  f32x4 acc[2][2] = {};

  LOAD(0); STORE(0);
  if (nt > 1) LOAD(1);
  __syncthreads();

  for (int t = 0; t < nt; ++t) {
    const int cur = t & 1;
    bf16x8 bh[2], bl[2], ah[2], al[2];
#pragma unroll
    for (int n = 0; n < 2; ++n) {
      bh[n] = *(const bf16x8*)&Bhs[cur][wc + n * 16 + fr][fk];
      bl[n] = *(const bf16x8*)&Bls[cur][wc + n * 16 + fr][fk];
    }
#pragma unroll
    for (int m = 0; m < 2; ++m) {
      ah[m] = *(const bf16x8*)&Ahs[cur][wr + m * 16 + fr][fk];
      al[m] = *(const bf16x8*)&Als[cur][wr + m * 16 + fr][fk];
    }
#pragma unroll
    for (int m = 0; m < 2; ++m)
#pragma unroll
      for (int n = 0; n < 2; ++n) {
        acc[m][n] = __builtin_amdgcn_mfma_f32_16x16x32_bf16(ah[m], bh[n], acc[m][n], 0, 0, 0);
        acc[m][n] = __builtin_amdgcn_mfma_f32_16x16x32_bf16(al[m], bh[n], acc[m][n], 0, 0, 0);
        acc[m][n] = __builtin_amdgcn_mfma_f32_16x16x32_bf16(ah[m], bl[n], acc[m][n], 0, 0, 0);
      }
    if (t + 1 < nt) {
      STORE(cur ^ 1);                // tile t+1 regs -> other buffer
      if (t + 2 < nt) LOAD(t + 2);   // prefetch tile t+2
    }
    __syncthreads();                 // single barrier per K-tile
  }

  // epilogue: C/D layout col = lane&15, row = (lane>>4)*4 + j  [m89-verified]
  const int fq = lane >> 4;
#pragma unroll
  for (int n = 0; n < 2; ++n) {
    const int col = col0 + wc + n * 16 + fr;
    const float bv = jb.bias ? jb.bias[col] : 0.f;
#pragma unroll
    for (int m = 0; m < 2; ++m) {
      const int rbase = row0 + wr + m * 16 + fq * 4;
#pragma unroll
      for (int jj = 0; jj < 4; ++jj) {
        float v = acc[m][n][jj] + bv;
        if (jb.relu) v = fmaxf(v, 0.f);
        const size_t idx = (size_t)(rbase + jj) * jb.N + col;
        if (jb.Cf) jb.Cf[idx] = v;
        if (jb.Ch) { ushort h, l; split1(v, h, l); jb.Ch[idx] = h; jb.Cl[idx] = l; }
      }
    }
  }
}

// ---------------------------------------------------------------------------
// ONE prep dispatch: 5 plain splits + 7 transpose+splits + 2 PARALLEL gemvs.
// ---------------------------------------------------------------------------
struct SplitJob { const float* src; ushort* hi; ushort* lo; int n4; };
struct TSJob { const float* src; ushort* hi; ushort* lo; int R, C; };
struct PrepArgs {
  SplitJob s[5];
  TSJob t[7];
  const float *img_b, *match_w, *match_b, *mh_wv, *mh_bv;
  float *bcomb;
  ushort *bt1pad_h, *bt1pad_l;      // [64,512], row 0 = split(bt1)
  int prefix[15];
};

__global__ __launch_bounds__(256) void prep_all(PrepArgs a) {
  int ji = 0;
  { const int bid = blockIdx.x;
    while (ji < 13 && bid >= a.prefix[ji + 1]) ++ji; }
  const int local = blockIdx.x - a.prefix[ji];
  const int t = threadIdx.x;
  __shared__ float tl[32][33];
  __shared__ float rr[4];

  if (ji < 5) {                       // plain split
    const SplitJob jb = a.s[ji];
    const int i = local * 256 + t;
    if (i < jb.n4) {
      float4 v = *(const float4*)&jb.src[(size_t)i * 4];
      ushort4 h, l;
      split1(v.x, h.x, l.x); split1(v.y, h.y, l.y);
      split1(v.z, h.z, l.z); split1(v.w, h.w, l.w);
      *(ushort4*)&jb.hi[(size_t)i * 4] = h;
      *(ushort4*)&jb.lo[(size_t)i * 4] = l;
    }
  } else if (ji < 12) {               // transpose + split
    const TSJob jb = a.t[ji - 5];
    const int ntx = jb.C / 32;
    const int r0 = (local / ntx) * 32, c0 = (local % ntx) * 32;
    const int tx = t & 31, ty = t >> 5;  // 32x8
#pragma unroll
    for (int i = 0; i < 32; i += 8)
      tl[ty + i][tx] = jb.src[(size_t)(r0 + ty + i) * jb.C + c0 + tx];
    __syncthreads();
#pragma unroll
    for (int i = 0; i < 32; i += 8) {
      ushort h, l; split1(tl[tx][ty + i], h, l);
      const size_t idx = (size_t)(c0 + ty + i) * jb.R + r0 + tx;
      jb.hi[idx] = h; jb.lo[idx] = l;
    }
  } else {                            // parallel gemv, 1 block per column
    const int j = local;              // 0..511
    const float* vec  = (ji == 12) ? a.img_b : a.match_b;
    const float* W    = (ji == 12) ? a.match_w : a.mh_wv;
    const float* badd = (ji == 12) ? a.match_b : a.mh_bv;
    float acc = 0.f;
    for (int k = t; k < kD; k += 256) acc = fmaf(vec[k], W[(size_t)k * kD + j], acc);
    for (int o = 32; o; o >>= 1) acc += __shfl_xor(acc, o);
    if ((t & 63) == 0) rr[t >> 6] = acc;
    __syncthreads();
    if (t == 0) {
      const float v = rr[0] + rr[1] + rr[2] + rr[3] + badd[j];
      if (ji == 12) a.bcomb[j] = v;
      else { ushort h, l; split1(v, h, l); a.bt1pad_h[j] = h; a.bt1pad_l[j] = l; }
    }
  }
}

// ---------------------------------------------------------------------------
// HETEROGENEOUS: blocks [0,160) = img GEMM (single-buffer 64x128, 30.7KB
// LDS); rest = wave-local float4 pool. Union LDS. (R15/R16-proven.)
// ---------------------------------------------------------------------------
struct PoolImgArgs {
  GemmJob g; int gemmBlocks;
  const float *ent_toks, *men_toks, *u;
  ushort *wh, *wl;
};

__global__ __launch_bounds__(256) void pool_img(PoolImgArgs a) {
  __shared__ ushort smem[15360];     // 30720 B union
  __shared__ float sm[4], sl[4];
  const int t = threadIdx.x;
  const int lane = t & 63, wave = t >> 6;

  if ((int)blockIdx.x < a.gemmBlocks) {
    ushort (*Ahs)[40] = (ushort(*)[40])&smem[0];
    ushort (*Als)[40] = (ushort(*)[40])&smem[2560];
    ushort (*Bhs)[40] = (ushort(*)[40])&smem[5120];
    ushort (*Bls)[40] = (ushort(*)[40])&smem[10240];
    const GemmJob jb = a.g;
    const int local = blockIdx.x;
    const int nbx = jb.N >> 7;
    const int by = local / nbx, bx = local - by * nbx;
    const int row0 = by * 64, col0 = bx * 128;
    const int K = jb.K;
    const int w = wave, fr = lane & 15, fk = (lane >> 4) * 8;
    const int sr = t >> 2, sk = (t & 3) * 8;
    f32x4 acc[4][2] = {};
    for (int k0 = 0; k0 < K; k0 += 32) {
      *(bf16x8*)&Ahs[sr][sk] = *(const bf16x8*)&jb.Ah[(size_t)(row0 + sr) * K + k0 + sk];
      *(bf16x8*)&Als[sr][sk] = *(const bf16x8*)&jb.Al[(size_t)(row0 + sr) * K + k0 + sk];
      *(bf16x8*)&Bhs[sr][sk] = *(const bf16x8*)&jb.Bh[(size_t)(col0 + sr) * K + k0 + sk];
      *(bf16x8*)&Bls[sr][sk] = *(const bf16x8*)&jb.Bl[(size_t)(col0 + sr) * K + k0 + sk];
      *(bf16x8*)&Bhs[64 + sr][sk] = *(const bf16x8*)&jb.Bh[(size_t)(col0 + 64 + sr) * K + k0 + sk];
      *(bf16x8*)&Bls[64 + sr][sk] = *(const bf16x8*)&jb.Bl[(size_t)(col0 + 64 + sr) * K + k0 + sk];
      __syncthreads();
      bf16x8 bh[2], bl[2];
#pragma unroll
      for (int n = 0; n < 2; ++n) {
        bh[n] = *(const bf16x8*)&Bhs[w * 32 + n * 16 + fr][fk];
        bl[n] = *(const bf16x8*)&Bls[w * 32 + n * 16 + fr][fk];
      }
#pragma unroll
      for (int m = 0; m < 4; ++m) {
        bf16x8 ah = *(const bf16x8*)&Ahs[m * 16 + fr][fk];
        bf16x8 al = *(const bf16x8*)&Als[m * 16 + fr][fk];
#pragma unroll
        for (int n = 0; n < 2; ++n) {
          acc[m][n] = __builtin_amdgcn_mfma_f32_16x16x32_bf16(ah, bh[n], acc[m][n], 0, 0, 0);
          acc[m][n] = __builtin_amdgcn_mfma_f32_16x16x32_bf16(al, bh[n], acc[m][n], 0, 0, 0);
          acc[m][n] = __builtin_amdgcn_mfma_f32_16x16x32_bf16(ah, bl[n], acc[m][n], 0, 0, 0);
        }
      }
      __syncthreads();
    }
    const int fq = lane >> 4;
#pragma unroll
    for (int n = 0; n < 2; ++n) {
      const int col = col0 + w * 32 + n * 16 + fr;
      const float bv = jb.bias ? jb.bias[col] : 0.f;
#pragma unroll
      for (int m = 0; m < 4; ++m) {
        const int rbase = row0 + m * 16 + fq * 4;
#pragma unroll
        for (int jj = 0; jj < 4; ++jj) {
          float v = acc[m][n][jj] + bv;
          if (jb.relu) v = fmaxf(v, 0.f);
          const size_t idx = (size_t)(rbase + jj) * jb.N + col;
          if (jb.Cf) jb.Cf[idx] = v;
          if (jb.Ch) { ushort h, l; split1(v, h, l); jb.Ch[idx] = h; jb.Cl[idx] = l; }
        }
      }
    }
    return;
  }

  // -------- pool path (float4 loads; lane owns dims 4*lane + 256*r) --------
  float* sacc = (float*)smem;        // [4][768]
  const int n = blockIdx.x - a.gemmBlocks;
  const float* toks = (n < kNE) ? a.ent_toks + (size_t)n * kP * kDin
                                : a.men_toks + (size_t)(n - kNE) * kP * kDin;
  const float* un = a.u + (size_t)n * kDin;
  const float scale = 0.044194173824159216f;  // 512^-0.5

  f32x4 ureg[3];
#pragma unroll
  for (int r = 0; r < 3; ++r) ureg[r] = *(const f32x4*)&un[4 * lane + 256 * r];

  float m = -INFINITY, l = 0.f;
  f32x4 acc[3] = {};

  for (int p = wave; p < kP; p += 4) {
    const float* tp = toks + (size_t)p * kDin;
    f32x4 tv[3];
#pragma unroll
    for (int r = 0; r < 3; ++r) tv[r] = *(const f32x4*)&tp[4 * lane + 256 * r];
    float d = 0.f;
#pragma unroll
    for (int r = 0; r < 3; ++r)
#pragma unroll
      for (int i = 0; i < 4; ++i) d = fmaf(tv[r][i], ureg[r][i], d);
    for (int o = 32; o; o >>= 1) d += __shfl_xor(d, o);   // wave-local reduce
    const float s = d * scale;
    const float mn = fmaxf(m, s);
    const float c = __expf(m - mn);   // 0 on first iter (m=-inf)
    const float e = __expf(s - mn);
    l = l * c + e;
#pragma unroll
    for (int r = 0; r < 3; ++r) acc[r] = acc[r] * c + tv[r] * e;
    m = mn;
  }

  // combine 4 wave-partials (one barrier)
#pragma unroll
  for (int r = 0; r < 3; ++r)
    *(f32x4*)&sacc[wave * kDin + 4 * lane + 256 * r] = acc[r];
  if (lane == 0) { sm[wave] = m; sl[wave] = l; }
  __syncthreads();

  const float M = fmaxf(fmaxf(sm[0], sm[1]), fmaxf(sm[2], sm[3]));
  const float c0 = __expf(sm[0] - M), c1 = __expf(sm[1] - M);
  const float c2 = __expf(sm[2] - M), c3 = __expf(sm[3] - M);
  const float inv = 1.f / (sl[0] * c0 + sl[1] * c1 + sl[2] * c2 + sl[3] * c3);

  const size_t base = (size_t)n * kDin;
#pragma unroll
  for (int r = 0; r < 3; ++r) {
    const int dd = t + r * 256;
    const float v = (sacc[0 * kDin + dd] * c0 + sacc[1 * kDin + dd] * c1 +
                     sacc[2 * kDin + dd] * c2 + sacc[3 * kDin + dd] * c3) * inv;
    ushort h, lo; split1(v, h, lo);
    a.wh[base + dd] = h; a.wl[base + dd] = lo;
  }
}

// ---------------------------------------------------------------------------
// Finalize with fused MoE gate (R13-proven).
// ---------------------------------------------------------------------------
__global__ __launch_bounds__(256) void finalize_ln(
    const float* __restrict__ cls_p, const float* __restrict__ et,
    const float* __restrict__ ei, const float* __restrict__ txt,
    const float* __restrict__ img,
    const float* __restrict__ gw, const float* __restrict__ gb,
    const float* __restrict__ gfw, const float* __restrict__ gfb,
    const float* __restrict__ lng, const float* __restrict__ lnb,
    ushort* __restrict__ ch, ushort* __restrict__ cl) {
  const int n = blockIdx.x;
  const int t = threadIdx.x;
  const int lane = t & 63, wave = t >> 6;
  const size_t base = (size_t)n * kD;
  const float c0 = cls_p[base + t], c1 = cls_p[base + 256 + t];

  const float t0 = txt[base + t], t1 = txt[base + 256 + t];
  const float i0 = img[base + t], i1 = img[base + 256 + t];
  float d  = fmaf(c0, gfw[t], c1 * gfw[t + 256]);
  float p0 = fmaf(t0, gw[t * 2 + 0], fmaf(t1, gw[(t + 256) * 2 + 0],
             fmaf(i0, gw[(512 + t) * 2 + 0], i1 * gw[(768 + t) * 2 + 0])));
  float p1 = fmaf(t0, gw[t * 2 + 1], fmaf(t1, gw[(t + 256) * 2 + 1],
             fmaf(i0, gw[(512 + t) * 2 + 1], i1 * gw[(768 + t) * 2 + 1])));
  for (int o = 32; o; o >>= 1) {
    d += __shfl_xor(d, o); p0 += __shfl_xor(p0, o); p1 += __shfl_xor(p1, o);
  }
  __shared__ float rd[4], r0[4], r1[4];
  __shared__ float gtb, g0b, g1b;
  if (lane == 0) { rd[wave] = d; r0[wave] = p0; r1[wave] = p1; }
  __syncthreads();
  if (t == 0) {
    gtb = tanhf(rd[0] + rd[1] + rd[2] + rd[3] + gfb[0]);
    const float l0 = r0[0] + r0[1] + r0[2] + r0[3] + gb[0];
    const float l1 = r1[0] + r1[1] + r1[2] + r1[3] + gb[1];
    const float mm = fmaxf(l0, l1);
    const float e0 = __expf(l0 - mm), e1 = __expf(l1 - mm);
    const float inv = 1.f / (e0 + e1);
    g0b = e0 * inv; g1b = e1 * inv;
  }
  __syncthreads();
  const float gt = gtb, g0 = g0b, g1 = g1b;

  const float y0 = c0 * gt + g0 * et[base + t]       + g1 * ei[base + t];
  const float y1 = c1 * gt + g0 * et[base + 256 + t] + g1 * ei[base + 256 + t];

  float s = y0 + y1, ss = fmaf(y0, y0, y1 * y1);
  for (int o = 32; o; o >>= 1) { s += __shfl_xor(s, o); ss += __shfl_xor(ss, o); }
  __shared__ float rsum[4], rssq[4];
  __shared__ float mb, ivb;
  if (lane == 0) { rsum[wave] = s; rssq[wave] = ss; }
  __syncthreads();
  if (t == 0) {
    const float S  = rsum[0] + rsum[1] + rsum[2] + rsum[3];
    const float SS = rssq[0] + rssq[1] + rssq[2] + rssq[3];
    const float mm = S / (float)kD;
    const float v  = SS / (float)kD - mm * mm;
    mb = mm; ivb = rsqrtf(v + 1e-5f);
  }
  __syncthreads();
  const float mm = mb, iv = ivb;
  ushort h, l;
  split1((y0 - mm) * iv * lng[t] + lnb[t], h, l);
  ch[base + t] = h; cl[base + t] = l;
  split1((y1 - mm) * iv * lng[t + 256] + lnb[t + 256], h, l);
  ch[base + 256 + t] = h; cl[base + 256 + t] = l;
}

// ---------------------------------------------------------------------------
extern "C" void kernel_launch(void* const* d_in, const int* in_sizes, int n_in,
                              void* d_out, int out_size, void* d_ws, size_t ws_size,
                              hipStream_t stream) {
  const float* ent_cls  = (const float*)d_in[0];
  const float* ent_tok  = (const float*)d_in[1];
  const float* men_cls  = (const float*)d_in[2];
  const float* men_tok  = (const float*)d_in[3];
  const float* text_w   = (const float*)d_in[4];
  const float* text_b   = (const float*)d_in[5];
  const float* img_w    = (const float*)d_in[6];
  const float* img_b    = (const float*)d_in[7];
  const float* gate_w   = (const float*)d_in[8];
  const float* gate_b   = (const float*)d_in[9];
  const float* ln_g     = (const float*)d_in[10];
  const float* ln_b     = (const float*)d_in[11];
  const float* match_w  = (const float*)d_in[12];
  const float* match_b  = (const float*)d_in[13];
  // d_in[14..18] (mh_query, mh_wq, mh_bq, mh_wk, mh_bk) provably unused
  const float* mh_wv    = (const float*)d_in[19];
  const float* mh_bv    = (const float*)d_in[20];
  const float* mh_wo    = (const float*)d_in[21];
  const float* mh_bo    = (const float*)d_in[22];
  const float* moe_gw   = (const float*)d_in[23];
  const float* moe_gb   = (const float*)d_in[24];
  const float* moe_tw1  = (const float*)d_in[25];
  const float* moe_tb1  = (const float*)d_in[26];
  const float* moe_tw2  = (const float*)d_in[27];
  const float* moe_tb2  = (const float*)d_in[28];
  const float* moe_iw1  = (const float*)d_in[29];
  const float* moe_ib1  = (const float*)d_in[30];
  const float* moe_iw2  = (const float*)d_in[31];
  const float* moe_ib2  = (const float*)d_in[32];
  (void)ws_size; (void)n_in; (void)in_sizes; (void)out_size;

  char* base = (char*)d_ws;
  size_t off = 0;
  auto allocB = [&](size_t bytes) -> char* {
    char* p = base + off; off = (off + bytes + 255) & ~(size_t)255; return p;
  };
  auto allocF = [&](size_t n) { return (float*)allocB(n * 4); };
  auto allocU = [&](size_t n) { return (ushort*)allocB(n * 2); };

  // fp32 intermediates
  float* clsp_f = allocF((size_t)kNtot * kD);
  float* u_f    = allocF((size_t)kNtot * kDin);
  float* txt_f  = allocF((size_t)kNtot * kD);
  float* img_f  = allocF((size_t)kNtot * kD);
  float* et_f   = allocF((size_t)kNtot * kD);
  float* ei_f   = allocF((size_t)kNtot * kD);
  float* bcomb  = allocF(kD);
  float* bimg_pad = allocF((size_t)64 * kD);     // row 0 = bimg
  // split pairs
  auto pair = [&](size_t n, ushort*& h, ushort*& l) { h = allocU(n); l = allocU(n); };
  ushort *ent_h,*ent_l,*men_h,*men_l,*imgw_h,*imgw_l,*matw_h,*matw_l,*mhwv_h,*mhwv_l;
  pair((size_t)kNE * kDin, ent_h, ent_l);
  pair((size_t)kB * kDin, men_h, men_l);
  pair((size_t)kDin * kD, imgw_h, imgw_l);
  pair((size_t)kD * kD, matw_h, matw_l);
  pair((size_t)kD * kD, mhwv_h, mhwv_l);
  ushort *textWT_h,*textWT_l,*matchWT_h,*matchWT_l,*mhWoT_h,*mhWoT_l;
  ushort *tw1T_h,*tw1T_l,*tw2T_h,*tw2T_l,*iw1T_h,*iw1T_l,*iw2T_h,*iw2T_l;
  pair((size_t)kD * kDin, textWT_h, textWT_l);
  pair((size_t)kD * kD, matchWT_h, matchWT_l);
  pair((size_t)kD * kD, mhWoT_h, mhWoT_l);
  pair((size_t)kD * kD, tw1T_h, tw1T_l);
  pair((size_t)kD * kD, tw2T_h, tw2T_l);
  pair((size_t)kD * kD, iw1T_h, iw1T_l);
  pair((size_t)kD * kD, iw2T_h, iw2T_l);
  ushort *clsp_h,*clsp_l,*U_h,*U_l,*WcombT_h,*WcombT_l,*WimgT_h,*WimgT_l;
  ushort *bt1pad_h,*bt1pad_l;
  pair((size_t)kNtot * kD, clsp_h, clsp_l);
  pair((size_t)kD * kD, U_h, U_l);
  pair((size_t)kD * kDin, WcombT_h, WcombT_l);
  pair((size_t)kD * kD, WimgT_h, WimgT_l);
  pair((size_t)64 * kD, bt1pad_h, bt1pad_l);     // rows 1-63 unused
  ushort *ws_h,*ws_l,*txt_h,*txt_l,*img_h,*img_l,*ht_h,*ht_l,*hi_h,*hi_l,*ctx_h,*ctx_l;
  pair((size_t)kNtot * kDin, ws_h, ws_l);
  pair((size_t)kNtot * kD, txt_h, txt_l);
  pair((size_t)kNtot * kD, img_h, img_l);
  pair((size_t)kNtot * kD, ht_h, ht_l);
  pair((size_t)kNtot * kD, hi_h, hi_l);
  pair((size_t)kNtot * kD, ctx_h, ctx_l);

  auto nblk = [](const GemmJob& j) { return (j.M / 64) * (j.N / 64); };
  auto launch_batch = [&](int njobs, GemmJob j0, GemmJob j1 = {}, GemmJob j2 = {},
                          GemmJob j3 = {}, GemmJob j4 = {}, GemmJob j5 = {}) {
    GemmBatch b{};
    b.j[0] = j0; b.j[1] = j1; b.j[2] = j2; b.j[3] = j3; b.j[4] = j4; b.j[5] = j5;
    b.prefix[0] = 0;
    for (int i = 0; i < 6; ++i)
      b.prefix[i + 1] = b.prefix[i] + (i < njobs ? nblk(b.j[i]) : 0);
    hipLaunchKernelGGL(gemm_batch, dim3(b.prefix[njobs]), 256, 0, stream, b);
  };

  // P0: ONE prep dispatch (5 splits + 7 trans-splits + 2 parallel gemvs)
  PrepArgs pa{};
  pa.s[0] = { ent_cls, ent_h, ent_l, kNE * kDin / 4 };
  pa.s[1] = { men_cls, men_h, men_l, kB * kDin / 4 };
  pa.s[2] = { img_w,   imgw_h, imgw_l, kDin * kD / 4 };
  pa.s[3] = { match_w, matw_h, matw_l, kD * kD / 4 };
  pa.s[4] = { mh_wv,   mhwv_h, mhwv_l, kD * kD / 4 };
  pa.t[0] = { text_w,  textWT_h,  textWT_l,  kDin, kD };
  pa.t[1] = { match_w, matchWT_h, matchWT_l, kD,   kD };
  pa.t[2] = { mh_wo,   mhWoT_h,   mhWoT_l,   kD,   kD };
  pa.t[3] = { moe_tw1, tw1T_h,    tw1T_l,    kD,   kD };
  pa.t[4] = { moe_tw2, tw2T_h,    tw2T_l,    kD,   kD };
  pa.t[5] = { moe_iw1, iw1T_h,    iw1T_l,    kD,   kD };
  pa.t[6] = { moe_iw2, iw2T_h,    iw2T_l,    kD,   kD };
  pa.img_b = img_b; pa.match_w = match_w; pa.match_b = match_b;
  pa.mh_wv = mh_wv; pa.mh_bv = mh_bv;
  pa.bcomb = bcomb; pa.bt1pad_h = bt1pad_h; pa.bt1pad_l = bt1pad_l;
  {
    int pfx = 0; int c = 0;
    pa.prefix[c++] = 0;
    for (int i = 0; i < 5; ++i) { pfx += (pa.s[i].n4 + 255) / 256; pa.prefix[c++] = pfx; }
    for (int i = 0; i < 7; ++i) { pfx += (pa.t[i].R / 32) * (pa.t[i].C / 32); pa.prefix[c++] = pfx; }
    for (int i = 0; i < 2; ++i) { pfx += kD; pa.prefix[c++] = pfx; }
    hipLaunchKernelGGL(prep_all, dim3(pfx), 256, 0, stream, pa);
  }

  // G1: clsp(ent), clsp(men), WcombT, U, bimg_pad = bt1pad@mhWoT^T + mh_bo
  launch_batch(5,
    GemmJob{ ent_h, ent_l, textWT_h, textWT_l, text_b,
             clsp_f, clsp_h, clsp_l, kNE, kD, kDin, 0 },
    GemmJob{ men_h, men_l, textWT_h, textWT_l, text_b,
             clsp_f + (size_t)kNE * kD, clsp_h + (size_t)kNE * kD,
             clsp_l + (size_t)kNE * kD, kB, kD, kDin, 0 },
    GemmJob{ matchWT_h, matchWT_l, imgw_h, imgw_l, nullptr,
             nullptr, WcombT_h, WcombT_l, kD, kDin, kD, 0 },
    GemmJob{ mhWoT_h, mhWoT_l, mhwv_h, mhwv_l, nullptr,
             nullptr, U_h, U_l, kD, kD, kD, 0 },
    GemmJob{ bt1pad_h, bt1pad_l, mhWoT_h, mhWoT_l, mh_bo,
             bimg_pad, nullptr, nullptr, 64, kD, kD, 0 });

  // G2: u = cls_p@img_w^T (fp32 only, K=512), WimgT = U@match_w^T
  launch_batch(2,
    GemmJob{ clsp_h, clsp_l, imgw_h, imgw_l, nullptr,
             u_f, nullptr, nullptr, kNtot, kDin, kD, 0 },
    GemmJob{ U_h, U_l, matw_h, matw_l, nullptr,
             nullptr, WimgT_h, WimgT_l, kD, kD, kD, 0 });

  // M1: img GEMM (160 blocks, 64x128, pool-independent) + float4 pool (2560)
  {
    PoolImgArgs pia{};
    pia.g = GemmJob{ clsp_h, clsp_l, WimgT_h, WimgT_l, bimg_pad,
                     img_f, img_h, img_l, kNtot, kD, kD, 0 };
    pia.gemmBlocks = (kNtot / 64) * (kD / 128);   // 160
    pia.ent_toks = ent_tok; pia.men_toks = men_tok; pia.u = u_f;
    pia.wh = ws_h; pia.wl = ws_l;
    hipLaunchKernelGGL(pool_img, dim3(pia.gemmBlocks + kNtot), 256, 0, stream, pia);
  }

  // G3: txt = ws@Wcomb + bcomb   [320 blocks]
  launch_batch(1,
    GemmJob{ ws_h, ws_l, WcombT_h, WcombT_l, bcomb,
             txt_f, txt_h, txt_l, kNtot, kD, kDin, 0 });

  // G4: expert hidden layers (relu, split only)   [640 blocks]
  launch_batch(2,
    GemmJob{ txt_h, txt_l, tw1T_h, tw1T_l, moe_tb1,
             nullptr, ht_h, ht_l, kNtot, kD, kD, 1 },
    GemmJob{ img_h, img_l, iw1T_h, iw1T_l, moe_ib1,
             nullptr, hi_h, hi_l, kNtot, kD, kD, 1 });

  // G5: expert output layers (fp32 only)   [640 blocks]
  launch_batch(2,
    GemmJob{ ht_h, ht_l, tw2T_h, tw2T_l, moe_tb2,
             et_f, nullptr, nullptr, kNtot, kD, kD, 0 },
    GemmJob{ hi_h, hi_l, iw2T_h, iw2T_l, moe_ib2,
             ei_f, nullptr, nullptr, kNtot, kD, kD, 0 });

  // P2: finalize (fused moe-gate + tanh-gate + combine + LN) -> ctx (split)
  hipLaunchKernelGGL(finalize_ln, dim3(kNtot), 256, 0, stream,
                     clsp_f, et_f, ei_f, txt_f, img_f,
                     moe_gw, moe_gb, gate_w, gate_b, ln_g, ln_b, ctx_h, ctx_l);

  // G6: out = m_ctx @ e_ctx^T
  launch_batch(1,
    GemmJob{ ctx_h + (size_t)kNE * kD, ctx_l + (size_t)kNE * kD,
             ctx_h, ctx_l, nullptr,
             (float*)d_out, nullptr, nullptr, kB, kNE, kD, 0 });
}